// Round 10
// baseline (1772.379 us; speedup 1.0000x reference)
//
#include <hip/hip_runtime.h>
#include <hip/hip_bf16.h>

typedef __hip_bfloat16 bf16;
typedef __attribute__((ext_vector_type(8))) short s8;   // 8 x bf16 MFMA A/B frag
typedef __attribute__((ext_vector_type(4))) float f4;   // MFMA C/D frag

#define N_FEA   3145728   // 2*96*128*128
#define N_EN    196608    // 2*96*32*32
#define N_E1    786432    // 2*96*64*64
#define OUT_EN  3145728
#define OUT_Q   3342336

__device__ __forceinline__ float b2f(bf16 v) { return __bfloat162float(v); }

// ---- stride-1 direct conv, H=W=128, PX=2, OCB oc/block, XCD-banded strips ----
// Block = (b, oc-group, strip of 512 px = 4 rows). bid&7 selects the 16-row band
// so each XCD's L2 holds one band (~3.5 MB). Weights for the group staged in LDS.
template <int OCB, int CINT>
__global__ __launch_bounds__(256) void conv3x3_s1(
    const float* __restrict__ in0, int c0,
    const float* __restrict__ in1, int c1,
    const float* __restrict__ w, const float* __restrict__ bias,
    float* __restrict__ out, int Cout, int relu) {
    const int W = 128, H = 128;
    const int NOC = Cout / OCB;
    int bid = blockIdx.x;
    const int rxcd = bid & 7;
    int r = bid >> 3;
    const int ocg = r % NOC;
    int t = r / NOC;                 // 0..7
    const int b = t >> 2;
    const int strip = rxcd * 4 + (t & 3);   // 0..31, rows strip*4..+3
    const int oc0 = ocg * OCB;
    const int Cin = c0 + c1;
    __shared__ float wl[OCB * 9 * CINT];
    for (int i = threadIdx.x; i < OCB * Cin * 9; i += 256) {
        int o = i / (Cin * 9), rem = i % (Cin * 9);
        wl[i] = w[(long)(oc0 + o) * Cin * 9 + rem];
    }
    __syncthreads();
    const int tid = threadIdx.x;
    const int ry = tid >> 6;                 // 0..3
    const int ox = (tid & 63) << 1;          // 0,2,..,126
    const int oy = strip * 4 + ry;
    const int iy0 = oy - 1, ixb = ox - 1;
    float acc[OCB][2];
#pragma unroll
    for (int o = 0; o < OCB; ++o) {
        float bz = bias[oc0 + o];
        acc[o][0] = bz; acc[o][1] = bz;
    }
    const bool fast = (ixb >= 0) && (ixb + 3 < W);

    auto seg = [&](const float* base, int nc, int wofs) {
        const float* pl = base + (long)b * nc * H * W;
        for (int c = 0; c < nc; ++c) {
#pragma unroll
            for (int ky = 0; ky < 3; ++ky) {
                int iy = iy0 + ky;
                if ((unsigned)iy >= (unsigned)H) continue;
                const float* row = pl + (long)iy * W + ixb;
                float rr[4];
                if (fast) {
#pragma unroll
                    for (int i = 0; i < 4; ++i) rr[i] = row[i];
                } else {
#pragma unroll
                    for (int i = 0; i < 4; ++i) {
                        int col = ixb + i;
                        rr[i] = ((unsigned)col < (unsigned)W) ? row[i] : 0.f;
                    }
                }
#pragma unroll
                for (int o = 0; o < OCB; ++o) {
                    const float* wv = &wl[(o * Cin + wofs + c) * 9 + ky * 3];
#pragma unroll
                    for (int j = 0; j < 2; ++j)
#pragma unroll
                        for (int kx = 0; kx < 3; ++kx)
                            acc[o][j] = fmaf(rr[j + kx], wv[kx], acc[o][j]);
                }
            }
            pl += (long)H * W;
        }
    };
    seg(in0, c0, 0);
    seg(in1, c1, c0);

#pragma unroll
    for (int o = 0; o < OCB; ++o) {
        long idx = (((long)b * Cout + oc0 + o) * H + oy) * W + ox;
#pragma unroll
        for (int j = 0; j < 2; ++j) {
            float a = acc[o][j];
            if (relu) a = a > 0.f ? a : 0.1f * a;
            out[idx + j] = a;
        }
    }
}

// ---------------- generic direct conv (stride 2 users), PX=4 ----------------
// If qq!=nullptr: fused quantization epilogue (out=en, qq=round(en), qf=round(en)).
template <int S, int OCB>
__global__ __launch_bounds__(256, 2) void conv3x3_v2(
    const float* __restrict__ in0, int c0,
    const float* __restrict__ in1, int c1,
    const float* __restrict__ w, const float* __restrict__ bias,
    float* __restrict__ out,
    int Cout, int Hin, int Win, int relu,
    float* __restrict__ qq, float* __restrict__ qf2) {
    const int Hout = (Hin - 1) / S + 1, Wout = (Win - 1) / S + 1;
    const int strips = (Hout * Wout) / 1024;
    int bid = blockIdx.x;
    const int strip = bid % strips; bid /= strips;
    const int oc0 = (bid % (Cout / OCB)) * OCB;
    const int b = bid / (Cout / OCB);
    const int Cin = c0 + c1;
    __shared__ float wl[OCB * 1728];
    for (int i = threadIdx.x; i < OCB * Cin * 9; i += 256) {
        int o = i / (Cin * 9), rem = i % (Cin * 9);
        wl[i] = w[(long)(oc0 + o) * Cin * 9 + rem];
    }
    __syncthreads();
    const int pix = strip * 1024 + threadIdx.x * 4;
    const int oy = pix / Wout, oxb = pix % Wout;
    const int iy0 = oy * S - 1, ixb = oxb * S - 1;
    constexpr int NX = 3 * S + 3;
    float acc[OCB][4];
#pragma unroll
    for (int o = 0; o < OCB; ++o) {
        float bz = bias[oc0 + o];
#pragma unroll
        for (int j = 0; j < 4; ++j) acc[o][j] = bz;
    }
    const bool fast = (ixb >= 0) && (ixb + NX - 1 < Win);

    auto seg = [&](const float* base, int nc, int wofs) {
        const float* pl = base + (long)b * nc * Hin * Win;
        for (int c = 0; c < nc; ++c) {
#pragma unroll
            for (int ky = 0; ky < 3; ++ky) {
                int iy = iy0 + ky;
                if ((unsigned)iy >= (unsigned)Hin) continue;
                const float* row = pl + (long)iy * Win + ixb;
                float rr[NX];
                if (fast) {
#pragma unroll
                    for (int i = 0; i < NX; ++i) rr[i] = row[i];
                } else {
#pragma unroll
                    for (int i = 0; i < NX; ++i) {
                        int col = ixb + i;
                        rr[i] = ((unsigned)col < (unsigned)Win) ? row[i] : 0.f;
                    }
                }
#pragma unroll
                for (int o = 0; o < OCB; ++o) {
                    const float* wv = &wl[(o * Cin + wofs + c) * 9 + ky * 3];
#pragma unroll
                    for (int j = 0; j < 4; ++j)
#pragma unroll
                        for (int kx = 0; kx < 3; ++kx)
                            acc[o][j] = fmaf(rr[j * S + kx], wv[kx], acc[o][j]);
                }
            }
            pl += (long)Hin * Win;
        }
    };
    seg(in0, c0, 0);
    seg(in1, c1, c0);

#pragma unroll
    for (int o = 0; o < OCB; ++o) {
        long idx = (((long)b * Cout + oc0 + o) * Hout + oy) * Wout + oxb;
#pragma unroll
        for (int j = 0; j < 4; ++j) {
            float a = acc[o][j];
            if (relu) a = a > 0.f ? a : 0.1f * a;
            out[idx + j] = a;
            if (qq) {
                float q = rintf(a);
                qq[idx + j] = q;
                qf2[idx + j] = q;
            }
        }
    }
}

// ------------- ConvTranspose2d(96->96,k3,s2,p1,op1), gather, 4 ox/thread --------------
template <int HWC>
__global__ __launch_bounds__(256) void convt3x3_v2(
    const float* __restrict__ in, const float* __restrict__ w,
    const float* __restrict__ bias, void* __restrict__ out,
    int Hin, int Win, int relu) {
    const int C = 96;
    const int Hout = 2 * Hin, Wout = 2 * Win;
    const int strips = (Hout * Wout) / 1024;
    int bid = blockIdx.x;
    const int strip = bid % strips; bid /= strips;
    const int oc = bid % C;
    const int b = bid / C;
    __shared__ float wl[864];
    for (int i = threadIdx.x; i < C * 9; i += 256) {
        int c = i / 9, k = i % 9;
        wl[i] = w[((long)c * C + oc) * 9 + k];
    }
    __syncthreads();
    const int pix = strip * 1024 + threadIdx.x * 4;
    const int oy = pix / Wout, oxb = pix % Wout;
    const int c0x = oxb >> 1;
    const int oyE = oy + 1;
    float acc[4];
    const float bz = bias[oc];
#pragma unroll
    for (int j = 0; j < 4; ++j) acc[j] = bz;
    const bool r2ok = (c0x + 2) < Win;

    const float* pl = in + (long)b * C * Hin * Win;
    for (int c = 0; c < C; ++c) {
        float wv[9];
#pragma unroll
        for (int k = 0; k < 9; ++k) wv[k] = wl[c * 9 + k];
#pragma unroll
        for (int ky = 0; ky < 3; ++ky) {
            int ty = oyE - ky;
            if (ty & 1) continue;
            int iy = ty >> 1;
            if ((unsigned)iy >= (unsigned)Hin) continue;
            const float* row = pl + (long)iy * Win + c0x;
            float r0 = row[0];
            float r1 = row[1];
            float r2 = r2ok ? row[2] : 0.f;
            acc[0] = fmaf(r0, wv[ky * 3 + 1], acc[0]);
            acc[1] = fmaf(r1, wv[ky * 3 + 0], acc[1]);
            acc[1] = fmaf(r0, wv[ky * 3 + 2], acc[1]);
            acc[2] = fmaf(r1, wv[ky * 3 + 1], acc[2]);
            acc[3] = fmaf(r2, wv[ky * 3 + 0], acc[3]);
            acc[3] = fmaf(r1, wv[ky * 3 + 2], acc[3]);
        }
        pl += (long)Hin * Win;
    }
#pragma unroll
    for (int j = 0; j < 4; ++j) {
        float a = acc[j];
        if (relu) a = a > 0.f ? a : 0.1f * a;
        if (HWC)
            ((bf16*)out)[((long)b * Hout * Wout + oy * Wout + oxb + j) * 96 + oc] =
                __float2bfloat16(a);
        else
            ((float*)out)[(((long)b * C + oc) * Hout + oy) * Wout + oxb + j] = a;
    }
}

// -------- combined weight transforms (1 launch): 3x MFMA-B pack + dcn transpose ------
__device__ __forceinline__ void packw(const float* __restrict__ w, bf16* __restrict__ wP,
                                      int Cin, int swap, long i) {
    const int cpt = Cin >> 5;
    int e = (int)(i & 7);
    int n16 = (int)((i >> 3) & 15);
    int q = (int)((i >> 7) & 3);
    long t = i >> 9;
    int ci = (int)(t % cpt); t /= cpt;
    int tap = (int)(t % 9);
    int g = (int)(t / 9);
    int oc = g * 16 + n16;
    int c = ci * 32 + q * 8 + e;
    int cs = swap ? (c + Cin / 2) % Cin : c;
    wP[i] = __float2bfloat16(w[((long)oc * Cin + cs) * 9 + tap]);
}
__global__ void wxform_all(const float* __restrict__ coffw, const float* __restrict__ ref1w,
                           const float* __restrict__ ref2w, const float* __restrict__ dcnw,
                           bf16* __restrict__ p_coff, bf16* __restrict__ p_ref1,
                           bf16* __restrict__ p_ref2, float* __restrict__ dwT) {
    const long n1 = 124416, n2 = 165888, n3 = 82944, n4 = 82944;
    long i = (long)blockIdx.x * 256 + threadIdx.x;
    if (i < n1) { packw(coffw, p_coff, 96, 0, i); return; }
    i -= n1;
    if (i < n2) { packw(ref1w, p_ref1, 192, 1, i); return; }
    i -= n2;
    if (i < n3) { packw(ref2w, p_ref2, 96, 0, i); return; }
    i -= n3;
    if (i < n4) {
        int oc = (int)(i % 96), k = (int)(i / 96);
        dwT[i] = dcnw[(long)oc * 864 + k];
    }
}

// -------- pack fp32 NCHW (96 ch) -> bf16 HWC [b][y][x][Cs] at channel offset --------
__global__ void pack_hwc(const float* __restrict__ src, bf16* __restrict__ dst,
                         int HW, int Cs, int coff) {
    long i = (long)blockIdx.x * 256 + threadIdx.x;
    if (i >= 2L * 96 * HW) return;
    int px = (int)(i % HW);
    long t = i / HW;
    int c = (int)(t % 96);
    int b = (int)(t / 96);
    dst[((long)b * HW + px) * Cs + coff + c] = __float2bfloat16(src[i]);
}

// ----------------- MFMA implicit-GEMM 3x3 conv (stride 1, 128x128) -----------------
template <int EPI>
__global__ __launch_bounds__(256) void mconv(
    const bf16* __restrict__ X, const bf16* __restrict__ wP,
    const float* __restrict__ bias, void* __restrict__ out,
    const bf16* __restrict__ res,
    int Cin, int Cout, int H, int W, int relu) {
    const int HW = H * W;
    const int NG = Cout >> 4, split = (NG + 1) >> 1;
    int bid = blockIdx.x;
    const int nb = HW >> 6;
    const int pxb = (bid % nb) << 6;
    const int b = bid / nb;
    const int wave = threadIdx.x >> 6, lane = threadIdx.x & 63;
    const int mt = (wave >> 1) << 5;
    const int og0 = (wave & 1) ? split : 0;
    const int og1 = (wave & 1) ? NG : split;
    const int q = lane >> 4, n16 = lane & 15;
    const int pA0 = pxb + mt + n16, pA1 = pA0 + 16;
    const int oy0 = pA0 / W, ox0 = pA0 % W;
    const int oy1 = pA1 / W, ox1 = pA1 % W;
    const long ib = (long)b * HW * Cin;
    f4 acc0[5], acc1[5];
    const f4 z4 = {0.f, 0.f, 0.f, 0.f};
#pragma unroll
    for (int g = 0; g < 5; ++g) { acc0[g] = z4; acc1[g] = z4; }
    const s8 z8 = {0, 0, 0, 0, 0, 0, 0, 0};
    const int cpt = Cin >> 5;
    const int lofs = lane << 3;
    for (int tap = 0; tap < 9; ++tap) {
        const int ky = tap / 3 - 1, kx = tap % 3 - 1;
        const int iy0 = oy0 + ky, ix0 = ox0 + kx;
        const int iy1 = oy1 + ky, ix1 = ox1 + kx;
        const bool v0 = (unsigned)iy0 < (unsigned)H && (unsigned)ix0 < (unsigned)W;
        const bool v1 = (unsigned)iy1 < (unsigned)H && (unsigned)ix1 < (unsigned)W;
        const bf16* pa0 = X + ib + ((long)iy0 * W + ix0) * Cin + q * 8;
        const bf16* pa1 = X + ib + ((long)iy1 * W + ix1) * Cin + q * 8;
        for (int ci = 0; ci < cpt; ++ci) {
            const int c0 = ci << 5;
            s8 a0 = v0 ? *(const s8*)(pa0 + c0) : z8;
            s8 a1 = v1 ? *(const s8*)(pa1 + c0) : z8;
#pragma unroll
            for (int gi = 0; gi < 5; ++gi) {
                int g = og0 + gi;
                if (g >= og1) break;
                s8 bb = *(const s8*)(wP + ((long)(g * 9 + tap) * cpt + ci) * 512 + lofs);
                acc0[gi] = __builtin_amdgcn_mfma_f32_16x16x32_bf16(a0, bb, acc0[gi], 0, 0, 0);
                acc1[gi] = __builtin_amdgcn_mfma_f32_16x16x32_bf16(a1, bb, acc1[gi], 0, 0, 0);
            }
        }
    }
#pragma unroll
    for (int gi = 0; gi < 5; ++gi) {
        int g = og0 + gi;
        if (g >= og1) break;
        int oc = g * 16 + n16;
        float bz = bias[oc];
#pragma unroll
        for (int t = 0; t < 2; ++t) {
            f4 a = t ? acc1[gi] : acc0[gi];
            int pxl = pxb + mt + t * 16 + q * 4;
#pragma unroll
            for (int r = 0; r < 4; ++r) {
                float v = a[r] + bz;
                if (relu) v = v > 0.f ? v : 0.1f * v;
                int px = pxl + r;
                if (EPI == 0)
                    ((bf16*)out)[((long)b * HW + px) * Cout + oc] = __float2bfloat16(v);
                else {
                    v += b2f(res[((long)b * HW + px) * 192 + 96 + oc]);
                    ((float*)out)[((long)b * Cout + oc) * HW + px] = v;
                }
            }
        }
    }
}

// -------- DCNv1 sample+contract (XCD-banded, bf16 LDS taps) --------
__global__ __launch_bounds__(128) void deform_lite_k(
    const float* __restrict__ x, const bf16* __restrict__ offs,
    const float* __restrict__ dwT, const float* __restrict__ db,
    bf16* __restrict__ X2) {
    const int H = 128, W = 128, C = 96;
    __shared__ float offL[4][144];
    __shared__ bf16 s[4][864];
    int bid = blockIdx.x;
    int rxcd = bid & 7;
    int i0 = bid >> 3;
    int b = i0 >> 9;
    int rem = i0 & 511;
    int oy = rxcd * 16 + (rem >> 5);
    int oxb = (rem & 31) << 2;
    int tid = threadIdx.x;
    long pxbase = (long)b * (H * W) + oy * W + oxb;
    for (int e = tid; e < 4 * 144; e += 128) {
        int p = e / 144, cc = e % 144;
        offL[p][cc] = b2f(offs[(pxbase + p) * 144 + cc]);
    }
    __syncthreads();
    for (int e = tid; e < 4 * 864; e += 128) {
        int p = e & 3;
        int t = e >> 2;
        int kk = t % 9, c = t / 9, g = c / 12;
        int ox = oxb + p;
        float offy = offL[p][g * 18 + kk * 2];
        float offx = offL[p][g * 18 + kk * 2 + 1];
        float py = (float)(oy + kk / 3 - 1) + offy;
        float px = (float)(ox + kk % 3 - 1) + offx;
        float y0f = floorf(py), x0f = floorf(px);
        float ly = py - y0f, lx = px - x0f;
        int y0 = (int)y0f, x0 = (int)x0f;
        const float* pl = x + ((long)b * C + c) * (long)H * W;
        float w00 = (1.f - ly) * (1.f - lx), w01 = (1.f - ly) * lx;
        float w10 = ly * (1.f - lx), w11 = ly * lx;
        float v = 0.f;
        if ((unsigned)y0 < (unsigned)H && (unsigned)x0 < (unsigned)W)
            v = fmaf(pl[y0 * W + x0], w00, v);
        if ((unsigned)y0 < (unsigned)H && (unsigned)(x0 + 1) < (unsigned)W)
            v = fmaf(pl[y0 * W + x0 + 1], w01, v);
        if ((unsigned)(y0 + 1) < (unsigned)H && (unsigned)x0 < (unsigned)W)
            v = fmaf(pl[(y0 + 1) * W + x0], w10, v);
        if ((unsigned)(y0 + 1) < (unsigned)H && (unsigned)(x0 + 1) < (unsigned)W)
            v = fmaf(pl[(y0 + 1) * W + x0 + 1], w11, v);
        s[p][c * 9 + kk] = __float2bfloat16(v);
    }
    __syncthreads();
    if (tid < C) {
        int oc = tid;
        float bz = db[oc];
        float a0 = bz, a1 = bz, a2 = bz, a3 = bz;
#pragma unroll 4
        for (int i = 0; i < 864; ++i) {
            float wv = dwT[i * 96 + oc];
            a0 = fmaf(b2f(s[0][i]), wv, a0);
            a1 = fmaf(b2f(s[1][i]), wv, a1);
            a2 = fmaf(b2f(s[2][i]), wv, a2);
            a3 = fmaf(b2f(s[3][i]), wv, a3);
        }
        long ob = ((long)b * 16384 + oy * 128 + oxb) * 192 + 96 + oc;
        X2[ob + 0 * 192] = __float2bfloat16(a0);
        X2[ob + 1 * 192] = __float2bfloat16(a1);
        X2[ob + 2 * 192] = __float2bfloat16(a2);
        X2[ob + 3 * 192] = __float2bfloat16(a3);
    }
}

extern "C" void kernel_launch(void* const* d_in, const int* in_sizes, int n_in,
                              void* d_out, int out_size, void* d_ws, size_t ws_size,
                              hipStream_t stream) {
    const float* ref_fea = (const float*)d_in[0];
    const float* inp_fea = (const float*)d_in[1];
    const float* oc1_w = (const float*)d_in[2];  const float* oc1_b = (const float*)d_in[3];
    const float* oc3_w = (const float*)d_in[4];  const float* oc3_b = (const float*)d_in[5];
    const float* enc1_w = (const float*)d_in[6]; const float* enc1_b = (const float*)d_in[7];
    const float* enc2_w = (const float*)d_in[8]; const float* enc2_b = (const float*)d_in[9];
    const float* dec1_w = (const float*)d_in[10]; const float* dec1_b = (const float*)d_in[11];
    const float* dec2_w = (const float*)d_in[12]; const float* dec2_b = (const float*)d_in[13];
    const float* coff_w = (const float*)d_in[14]; const float* coff_b = (const float*)d_in[15];
    const float* dcn_w = (const float*)d_in[16];  const float* dcn_b = (const float*)d_in[17];
    const float* ref1_w = (const float*)d_in[18]; const float* ref1_b = (const float*)d_in[19];
    const float* ref2_w = (const float*)d_in[20]; const float* ref2_b = (const float*)d_in[21];

    float* out = (float*)d_out;
    float* S1 = (float*)d_ws;             // 12.58 MB slot
    float* S2 = S1 + N_FEA;               // 12.58 MB slot
    float* F = S1 + N_E1;                 // q fp32 (after e1 region)
    bf16* de_hwc = (bf16*)S1;
    bf16* offs = (bf16*)S2;               // HWC [b][HW][144]
    bf16* X2 = (bf16*)S1;                 // [ref | aligned] HWC 192c
    bf16* r1 = (bf16*)S2;
    bf16* wtb = (bf16*)S2 + 4800000;      // tail at S2+9.6 MB
    bf16* wt_coff = wtb;                  // 124416
    bf16* wt_ref1 = wt_coff + 124416;     // 165888
    bf16* wt_ref2 = wt_ref1 + 165888;     // 82944
    float* dwT = (float*)(wt_ref2 + 82944);  // 864*96 fp32

    dim3 blk(256);
    auto nb = [](long n) { return dim3((unsigned)((n + 255) / 256)); };

    // ---- encoder (fp32-exact) ----
    conv3x3_s1<4, 192><<<dim3(1536), blk, 0, stream>>>(ref_fea, 96, inp_fea, 96,
                                                       oc1_w, oc1_b, S1, 96, 1);
    conv3x3_s1<4, 96><<<dim3(1536), blk, 0, stream>>>(S1, 96, S1, 0,
                                                      oc3_w, oc3_b, S2, 96, 1);
    conv3x3_v2<2, 1><<<dim3(2 * 96 * 4), blk, 0, stream>>>(S2, 96, S2, 0,
                                                           enc1_w, enc1_b, S1,
                                                           96, 128, 128, 1, nullptr, nullptr);
    // all weight transforms in one launch
    wxform_all<<<nb(124416L + 165888 + 82944 + 82944), blk, 0, stream>>>(
        coff_w, ref1_w, ref2_w, dcn_w, wt_coff, wt_ref1, wt_ref2, dwT);
    // enc2 + fused quantization: writes out1 (en), out2 (q) and F (q fp32)
    conv3x3_v2<2, 1><<<dim3(2 * 96), blk, 0, stream>>>(S1, 96, S1, 0,
                                                       enc2_w, enc2_b, out + OUT_EN,
                                                       96, 64, 64, 0, out + OUT_Q, F);
    // ---- decoder ----
    convt3x3_v2<0><<<dim3(2 * 96 * 4), blk, 0, stream>>>(F, dec1_w, dec1_b, S2, 32, 32, 1);
    convt3x3_v2<1><<<dim3(2 * 96 * 16), blk, 0, stream>>>(S2, dec2_w, dec2_b, de_hwc,
                                                          64, 64, 0);
    // ---- MFMA: offsets = conv(de) -> HWC bf16 ----
    mconv<0><<<dim3(512), blk, 0, stream>>>(de_hwc, wt_coff, coff_b, offs, nullptr,
                                            96, 144, 128, 128, 0);
    // ---- X2 = [ref | aligned] HWC ----
    pack_hwc<<<nb(N_FEA), blk, 0, stream>>>(ref_fea, X2, 16384, 192, 0);
    deform_lite_k<<<dim3(2 * 128 * 32), dim3(128), 0, stream>>>(ref_fea, offs,
                                                                dwT, dcn_b, X2);
    // ---- MFMA: r1 = lrelu(conv(X2, ref1)); out0 = aligned + lrelu(conv(r1, ref2)) ----
    mconv<0><<<dim3(512), blk, 0, stream>>>(X2, wt_ref1, ref1_b, r1, nullptr,
                                            192, 96, 128, 128, 1);
    mconv<3><<<dim3(512), blk, 0, stream>>>(r1, wt_ref2, ref2_b, out, X2,
                                            96, 96, 128, 128, 1);
}

// Round 11
// 1528.232 us; speedup vs baseline: 1.1598x; 1.1598x over previous
//
#include <hip/hip_runtime.h>
#include <hip/hip_bf16.h>

typedef __hip_bfloat16 bf16;
typedef __attribute__((ext_vector_type(8))) short s8;   // 8 x bf16 MFMA A/B frag
typedef __attribute__((ext_vector_type(4))) float f4;   // MFMA C/D frag

#define N_FEA   3145728   // 2*96*128*128
#define N_EN    196608    // 2*96*32*32
#define N_E1    786432    // 2*96*64*64
#define OUT_EN  3145728
#define OUT_Q   3342336

__device__ __forceinline__ float b2f(bf16 v) { return __bfloat162float(v); }

// ---- split-K stride-1 direct conv, 128x128, PX=4, OCB oc/block ----
// Grid = 2 x (b, ocg, strip): bid&1 selects the K-half. Each block writes a raw
// partial (no bias/act) to P0 or P1; fuse_add_k combines. Doubles resident waves.
template <int OCB>
__global__ __launch_bounds__(256) void conv3x3_split(
    const float* __restrict__ inA, int cA, int bstrA, int wofsA,
    const float* __restrict__ inB, int cB, int bstrB, int wofsB,
    const float* __restrict__ w, int wstride,
    float* __restrict__ P0, float* __restrict__ P1, int Cout) {
    const int H = 128, W = 128;
    const int NOC = Cout / OCB;
    int bid = blockIdx.x;
    const int ks = bid & 1;
    int r = bid >> 1;
    const int strip = r & 15; r >>= 4;
    const int ocg = r % NOC;
    const int b = r / NOC;
    const int oc0 = ocg * OCB;
    const float* in = ks ? inB : inA;
    const int cN = ks ? cB : cA;
    const int bstr = ks ? bstrB : bstrA;
    const int wofs = ks ? wofsB : wofsA;
    float* P = ks ? P1 : P0;
    __shared__ float wl[OCB * 96 * 9];          // up to 96 ch per half
    for (int i = threadIdx.x; i < OCB * cN * 9; i += 256) {
        int o = i / (cN * 9), rem = i % (cN * 9);
        int c = rem / 9, k = rem % 9;
        wl[i] = w[((long)(oc0 + o) * wstride + wofs + c) * 9 + k];
    }
    __syncthreads();
    const int pix = strip * 1024 + threadIdx.x * 4;
    const int oy = pix >> 7, oxb = pix & 127;
    const int iy0 = oy - 1, ixb = oxb - 1;
    float acc[OCB][4];
#pragma unroll
    for (int o = 0; o < OCB; ++o)
#pragma unroll
        for (int j = 0; j < 4; ++j) acc[o][j] = 0.f;
    const bool fast = (ixb >= 0) && (ixb + 5 < W);

    const float* pl = in + (long)b * bstr * H * W;
    for (int c = 0; c < cN; ++c) {
#pragma unroll
        for (int ky = 0; ky < 3; ++ky) {
            int iy = iy0 + ky;
            if ((unsigned)iy >= (unsigned)H) continue;
            const float* row = pl + (long)iy * W + ixb;
            float rr[6];
            if (fast) {
#pragma unroll
                for (int i = 0; i < 6; ++i) rr[i] = row[i];
            } else {
#pragma unroll
                for (int i = 0; i < 6; ++i) {
                    int col = ixb + i;
                    rr[i] = ((unsigned)col < (unsigned)W) ? row[i] : 0.f;
                }
            }
#pragma unroll
            for (int o = 0; o < OCB; ++o) {
                const float* wv = &wl[(o * cN + c) * 9 + ky * 3];
#pragma unroll
                for (int j = 0; j < 4; ++j)
#pragma unroll
                    for (int kx = 0; kx < 3; ++kx)
                        acc[o][j] = fmaf(rr[j + kx], wv[kx], acc[o][j]);
            }
        }
        pl += (long)H * W;
    }
#pragma unroll
    for (int o = 0; o < OCB; ++o) {
        long idx = (((long)b * Cout + oc0 + o) * H + oy) * W + oxb;
#pragma unroll
        for (int j = 0; j < 4; ++j) P[idx + j] = acc[o][j];
    }
}

// out = lrelu(bias + p0 + p1)
__global__ void fuse_add_k(const float* __restrict__ p0, const float* __restrict__ p1,
                           const float* __restrict__ bias, float* __restrict__ out) {
    long idx = (long)blockIdx.x * 256 + threadIdx.x;
    if (idx >= (long)N_FEA) return;
    int oc = (int)((idx >> 14) % 96);
    float a = bias[oc] + p0[idx] + p1[idx];
    out[idx] = a > 0.f ? a : 0.1f * a;
}

// ---------------- generic direct conv (stride 2 users), PX=4 ----------------
// If qq!=nullptr: fused quantization epilogue.
template <int S, int OCB>
__global__ __launch_bounds__(256, 2) void conv3x3_v2(
    const float* __restrict__ in0, int c0,
    const float* __restrict__ in1, int c1,
    const float* __restrict__ w, const float* __restrict__ bias,
    float* __restrict__ out,
    int Cout, int Hin, int Win, int relu,
    float* __restrict__ qq, float* __restrict__ qf2) {
    const int Hout = (Hin - 1) / S + 1, Wout = (Win - 1) / S + 1;
    const int strips = (Hout * Wout) / 1024;
    int bid = blockIdx.x;
    const int strip = bid % strips; bid /= strips;
    const int oc0 = (bid % (Cout / OCB)) * OCB;
    const int b = bid / (Cout / OCB);
    const int Cin = c0 + c1;
    __shared__ float wl[OCB * 1728];
    for (int i = threadIdx.x; i < OCB * Cin * 9; i += 256) {
        int o = i / (Cin * 9), rem = i % (Cin * 9);
        wl[i] = w[(long)(oc0 + o) * Cin * 9 + rem];
    }
    __syncthreads();
    const int pix = strip * 1024 + threadIdx.x * 4;
    const int oy = pix / Wout, oxb = pix % Wout;
    const int iy0 = oy * S - 1, ixb = oxb * S - 1;
    constexpr int NX = 3 * S + 3;
    float acc[OCB][4];
#pragma unroll
    for (int o = 0; o < OCB; ++o) {
        float bz = bias[oc0 + o];
#pragma unroll
        for (int j = 0; j < 4; ++j) acc[o][j] = bz;
    }
    const bool fast = (ixb >= 0) && (ixb + NX - 1 < Win);

    auto seg = [&](const float* base, int nc, int wofs) {
        const float* pl = base + (long)b * nc * Hin * Win;
        for (int c = 0; c < nc; ++c) {
#pragma unroll
            for (int ky = 0; ky < 3; ++ky) {
                int iy = iy0 + ky;
                if ((unsigned)iy >= (unsigned)Hin) continue;
                const float* row = pl + (long)iy * Win + ixb;
                float rr[NX];
                if (fast) {
#pragma unroll
                    for (int i = 0; i < NX; ++i) rr[i] = row[i];
                } else {
#pragma unroll
                    for (int i = 0; i < NX; ++i) {
                        int col = ixb + i;
                        rr[i] = ((unsigned)col < (unsigned)Win) ? row[i] : 0.f;
                    }
                }
#pragma unroll
                for (int o = 0; o < OCB; ++o) {
                    const float* wv = &wl[(o * Cin + wofs + c) * 9 + ky * 3];
#pragma unroll
                    for (int j = 0; j < 4; ++j)
#pragma unroll
                        for (int kx = 0; kx < 3; ++kx)
                            acc[o][j] = fmaf(rr[j * S + kx], wv[kx], acc[o][j]);
                }
            }
            pl += (long)Hin * Win;
        }
    };
    seg(in0, c0, 0);
    seg(in1, c1, c0);

#pragma unroll
    for (int o = 0; o < OCB; ++o) {
        long idx = (((long)b * Cout + oc0 + o) * Hout + oy) * Wout + oxb;
#pragma unroll
        for (int j = 0; j < 4; ++j) {
            float a = acc[o][j];
            if (relu) a = a > 0.f ? a : 0.1f * a;
            out[idx + j] = a;
            if (qq) {
                float q = rintf(a);
                qq[idx + j] = q;
                qf2[idx + j] = q;
            }
        }
    }
}

// ------------- ConvTranspose2d(96->96,k3,s2,p1,op1), gather, 4 ox/thread --------------
template <int HWC>
__global__ __launch_bounds__(256) void convt3x3_v2(
    const float* __restrict__ in, const float* __restrict__ w,
    const float* __restrict__ bias, void* __restrict__ out,
    int Hin, int Win, int relu) {
    const int C = 96;
    const int Hout = 2 * Hin, Wout = 2 * Win;
    const int strips = (Hout * Wout) / 1024;
    int bid = blockIdx.x;
    const int strip = bid % strips; bid /= strips;
    const int oc = bid % C;
    const int b = bid / C;
    __shared__ float wl[864];
    for (int i = threadIdx.x; i < C * 9; i += 256) {
        int c = i / 9, k = i % 9;
        wl[i] = w[((long)c * C + oc) * 9 + k];
    }
    __syncthreads();
    const int pix = strip * 1024 + threadIdx.x * 4;
    const int oy = pix / Wout, oxb = pix % Wout;
    const int c0x = oxb >> 1;
    const int oyE = oy + 1;
    float acc[4];
    const float bz = bias[oc];
#pragma unroll
    for (int j = 0; j < 4; ++j) acc[j] = bz;
    const bool r2ok = (c0x + 2) < Win;

    const float* pl = in + (long)b * C * Hin * Win;
    for (int c = 0; c < C; ++c) {
        float wv[9];
#pragma unroll
        for (int k = 0; k < 9; ++k) wv[k] = wl[c * 9 + k];
#pragma unroll
        for (int ky = 0; ky < 3; ++ky) {
            int ty = oyE - ky;
            if (ty & 1) continue;
            int iy = ty >> 1;
            if ((unsigned)iy >= (unsigned)Hin) continue;
            const float* row = pl + (long)iy * Win + c0x;
            float r0 = row[0];
            float r1 = row[1];
            float r2 = r2ok ? row[2] : 0.f;
            acc[0] = fmaf(r0, wv[ky * 3 + 1], acc[0]);
            acc[1] = fmaf(r1, wv[ky * 3 + 0], acc[1]);
            acc[1] = fmaf(r0, wv[ky * 3 + 2], acc[1]);
            acc[2] = fmaf(r1, wv[ky * 3 + 1], acc[2]);
            acc[3] = fmaf(r2, wv[ky * 3 + 0], acc[3]);
            acc[3] = fmaf(r1, wv[ky * 3 + 2], acc[3]);
        }
        pl += (long)Hin * Win;
    }
#pragma unroll
    for (int j = 0; j < 4; ++j) {
        float a = acc[j];
        if (relu) a = a > 0.f ? a : 0.1f * a;
        if (HWC)
            ((bf16*)out)[((long)b * Hout * Wout + oy * Wout + oxb + j) * 96 + oc] =
                __float2bfloat16(a);
        else
            ((float*)out)[(((long)b * C + oc) * Hout + oy) * Wout + oxb + j] = a;
    }
}

// -------- combined weight transforms (1 launch): 3x MFMA-B pack + dcn transpose ------
__device__ __forceinline__ void packw(const float* __restrict__ w, bf16* __restrict__ wP,
                                      int Cin, int swap, long i) {
    const int cpt = Cin >> 5;
    int e = (int)(i & 7);
    int n16 = (int)((i >> 3) & 15);
    int q = (int)((i >> 7) & 3);
    long t = i >> 9;
    int ci = (int)(t % cpt); t /= cpt;
    int tap = (int)(t % 9);
    int g = (int)(t / 9);
    int oc = g * 16 + n16;
    int c = ci * 32 + q * 8 + e;
    int cs = swap ? (c + Cin / 2) % Cin : c;
    wP[i] = __float2bfloat16(w[((long)oc * Cin + cs) * 9 + tap]);
}
__global__ void wxform_all(const float* __restrict__ coffw, const float* __restrict__ ref1w,
                           const float* __restrict__ ref2w, const float* __restrict__ dcnw,
                           bf16* __restrict__ p_coff, bf16* __restrict__ p_ref1,
                           bf16* __restrict__ p_ref2, float* __restrict__ dwT) {
    const long n1 = 124416, n2 = 165888, n3 = 82944, n4 = 82944;
    long i = (long)blockIdx.x * 256 + threadIdx.x;
    if (i < n1) { packw(coffw, p_coff, 96, 0, i); return; }
    i -= n1;
    if (i < n2) { packw(ref1w, p_ref1, 192, 1, i); return; }
    i -= n2;
    if (i < n3) { packw(ref2w, p_ref2, 96, 0, i); return; }
    i -= n3;
    if (i < n4) {
        int oc = (int)(i % 96), k = (int)(i / 96);
        dwT[i] = dcnw[(long)oc * 864 + k];
    }
}

// -------- pack fp32 NCHW (96 ch) -> bf16 HWC [b][y][x][Cs] at channel offset --------
__global__ void pack_hwc(const float* __restrict__ src, bf16* __restrict__ dst,
                         int HW, int Cs, int coff) {
    long i = (long)blockIdx.x * 256 + threadIdx.x;
    if (i >= 2L * 96 * HW) return;
    int px = (int)(i % HW);
    long t = i / HW;
    int c = (int)(t % 96);
    int b = (int)(t / 96);
    dst[((long)b * HW + px) * Cs + coff + c] = __float2bfloat16(src[i]);
}

// ----------------- MFMA implicit-GEMM 3x3 conv (stride 1, 128x128) -----------------
template <int EPI>
__global__ __launch_bounds__(256) void mconv(
    const bf16* __restrict__ X, const bf16* __restrict__ wP,
    const float* __restrict__ bias, void* __restrict__ out,
    const bf16* __restrict__ res,
    int Cin, int Cout, int H, int W, int relu) {
    const int HW = H * W;
    const int NG = Cout >> 4, split = (NG + 1) >> 1;
    int bid = blockIdx.x;
    const int nb = HW >> 6;
    const int pxb = (bid % nb) << 6;
    const int b = bid / nb;
    const int wave = threadIdx.x >> 6, lane = threadIdx.x & 63;
    const int mt = (wave >> 1) << 5;
    const int og0 = (wave & 1) ? split : 0;
    const int og1 = (wave & 1) ? NG : split;
    const int q = lane >> 4, n16 = lane & 15;
    const int pA0 = pxb + mt + n16, pA1 = pA0 + 16;
    const int oy0 = pA0 / W, ox0 = pA0 % W;
    const int oy1 = pA1 / W, ox1 = pA1 % W;
    const long ib = (long)b * HW * Cin;
    f4 acc0[5], acc1[5];
    const f4 z4 = {0.f, 0.f, 0.f, 0.f};
#pragma unroll
    for (int g = 0; g < 5; ++g) { acc0[g] = z4; acc1[g] = z4; }
    const s8 z8 = {0, 0, 0, 0, 0, 0, 0, 0};
    const int cpt = Cin >> 5;
    const int lofs = lane << 3;
    for (int tap = 0; tap < 9; ++tap) {
        const int ky = tap / 3 - 1, kx = tap % 3 - 1;
        const int iy0 = oy0 + ky, ix0 = ox0 + kx;
        const int iy1 = oy1 + ky, ix1 = ox1 + kx;
        const bool v0 = (unsigned)iy0 < (unsigned)H && (unsigned)ix0 < (unsigned)W;
        const bool v1 = (unsigned)iy1 < (unsigned)H && (unsigned)ix1 < (unsigned)W;
        const bf16* pa0 = X + ib + ((long)iy0 * W + ix0) * Cin + q * 8;
        const bf16* pa1 = X + ib + ((long)iy1 * W + ix1) * Cin + q * 8;
        for (int ci = 0; ci < cpt; ++ci) {
            const int c0 = ci << 5;
            s8 a0 = v0 ? *(const s8*)(pa0 + c0) : z8;
            s8 a1 = v1 ? *(const s8*)(pa1 + c0) : z8;
#pragma unroll
            for (int gi = 0; gi < 5; ++gi) {
                int g = og0 + gi;
                if (g >= og1) break;
                s8 bb = *(const s8*)(wP + ((long)(g * 9 + tap) * cpt + ci) * 512 + lofs);
                acc0[gi] = __builtin_amdgcn_mfma_f32_16x16x32_bf16(a0, bb, acc0[gi], 0, 0, 0);
                acc1[gi] = __builtin_amdgcn_mfma_f32_16x16x32_bf16(a1, bb, acc1[gi], 0, 0, 0);
            }
        }
    }
#pragma unroll
    for (int gi = 0; gi < 5; ++gi) {
        int g = og0 + gi;
        if (g >= og1) break;
        int oc = g * 16 + n16;
        float bz = bias[oc];
#pragma unroll
        for (int t = 0; t < 2; ++t) {
            f4 a = t ? acc1[gi] : acc0[gi];
            int pxl = pxb + mt + t * 16 + q * 4;
#pragma unroll
            for (int r = 0; r < 4; ++r) {
                float v = a[r] + bz;
                if (relu) v = v > 0.f ? v : 0.1f * v;
                int px = pxl + r;
                if (EPI == 0)
                    ((bf16*)out)[((long)b * HW + px) * Cout + oc] = __float2bfloat16(v);
                else {
                    v += b2f(res[((long)b * HW + px) * 192 + 96 + oc]);
                    ((float*)out)[((long)b * Cout + oc) * HW + px] = v;
                }
            }
        }
    }
}

// -------- DCNv1 sample+contract (XCD-banded, bf16 LDS taps) --------
__global__ __launch_bounds__(128) void deform_lite_k(
    const float* __restrict__ x, const bf16* __restrict__ offs,
    const float* __restrict__ dwT, const float* __restrict__ db,
    bf16* __restrict__ X2) {
    const int H = 128, W = 128, C = 96;
    __shared__ float offL[4][144];
    __shared__ bf16 s[4][864];
    int bid = blockIdx.x;
    int rxcd = bid & 7;
    int i0 = bid >> 3;
    int b = i0 >> 9;
    int rem = i0 & 511;
    int oy = rxcd * 16 + (rem >> 5);
    int oxb = (rem & 31) << 2;
    int tid = threadIdx.x;
    long pxbase = (long)b * (H * W) + oy * W + oxb;
    for (int e = tid; e < 4 * 144; e += 128) {
        int p = e / 144, cc = e % 144;
        offL[p][cc] = b2f(offs[(pxbase + p) * 144 + cc]);
    }
    __syncthreads();
    for (int e = tid; e < 4 * 864; e += 128) {
        int p = e & 3;
        int t = e >> 2;
        int kk = t % 9, c = t / 9, g = c / 12;
        int ox = oxb + p;
        float offy = offL[p][g * 18 + kk * 2];
        float offx = offL[p][g * 18 + kk * 2 + 1];
        float py = (float)(oy + kk / 3 - 1) + offy;
        float px = (float)(ox + kk % 3 - 1) + offx;
        float y0f = floorf(py), x0f = floorf(px);
        float ly = py - y0f, lx = px - x0f;
        int y0 = (int)y0f, x0 = (int)x0f;
        const float* pl = x + ((long)b * C + c) * (long)H * W;
        float w00 = (1.f - ly) * (1.f - lx), w01 = (1.f - ly) * lx;
        float w10 = ly * (1.f - lx), w11 = ly * lx;
        float v = 0.f;
        if ((unsigned)y0 < (unsigned)H && (unsigned)x0 < (unsigned)W)
            v = fmaf(pl[y0 * W + x0], w00, v);
        if ((unsigned)y0 < (unsigned)H && (unsigned)(x0 + 1) < (unsigned)W)
            v = fmaf(pl[y0 * W + x0 + 1], w01, v);
        if ((unsigned)(y0 + 1) < (unsigned)H && (unsigned)x0 < (unsigned)W)
            v = fmaf(pl[(y0 + 1) * W + x0], w10, v);
        if ((unsigned)(y0 + 1) < (unsigned)H && (unsigned)(x0 + 1) < (unsigned)W)
            v = fmaf(pl[(y0 + 1) * W + x0 + 1], w11, v);
        s[p][c * 9 + kk] = __float2bfloat16(v);
    }
    __syncthreads();
    if (tid < C) {
        int oc = tid;
        float bz = db[oc];
        float a0 = bz, a1 = bz, a2 = bz, a3 = bz;
#pragma unroll 4
        for (int i = 0; i < 864; ++i) {
            float wv = dwT[i * 96 + oc];
            a0 = fmaf(b2f(s[0][i]), wv, a0);
            a1 = fmaf(b2f(s[1][i]), wv, a1);
            a2 = fmaf(b2f(s[2][i]), wv, a2);
            a3 = fmaf(b2f(s[3][i]), wv, a3);
        }
        long ob = ((long)b * 16384 + oy * 128 + oxb) * 192 + 96 + oc;
        X2[ob + 0 * 192] = __float2bfloat16(a0);
        X2[ob + 1 * 192] = __float2bfloat16(a1);
        X2[ob + 2 * 192] = __float2bfloat16(a2);
        X2[ob + 3 * 192] = __float2bfloat16(a3);
    }
}

extern "C" void kernel_launch(void* const* d_in, const int* in_sizes, int n_in,
                              void* d_out, int out_size, void* d_ws, size_t ws_size,
                              hipStream_t stream) {
    const float* ref_fea = (const float*)d_in[0];
    const float* inp_fea = (const float*)d_in[1];
    const float* oc1_w = (const float*)d_in[2];  const float* oc1_b = (const float*)d_in[3];
    const float* oc3_w = (const float*)d_in[4];  const float* oc3_b = (const float*)d_in[5];
    const float* enc1_w = (const float*)d_in[6]; const float* enc1_b = (const float*)d_in[7];
    const float* enc2_w = (const float*)d_in[8]; const float* enc2_b = (const float*)d_in[9];
    const float* dec1_w = (const float*)d_in[10]; const float* dec1_b = (const float*)d_in[11];
    const float* dec2_w = (const float*)d_in[12]; const float* dec2_b = (const float*)d_in[13];
    const float* coff_w = (const float*)d_in[14]; const float* coff_b = (const float*)d_in[15];
    const float* dcn_w = (const float*)d_in[16];  const float* dcn_b = (const float*)d_in[17];
    const float* ref1_w = (const float*)d_in[18]; const float* ref1_b = (const float*)d_in[19];
    const float* ref2_w = (const float*)d_in[20]; const float* ref2_b = (const float*)d_in[21];

    float* out = (float*)d_out;
    float* OUTS = out;                    // out0 region as fp32 scratch (t1/t2)
    float* S1 = (float*)d_ws;             // 12.58 MB slot
    float* S2 = S1 + N_FEA;               // 12.58 MB slot
    float* F = S1 + N_E1;                 // q fp32 (after e1 region)
    bf16* de_hwc = (bf16*)S1;
    bf16* offs = (bf16*)S2;               // HWC [b][HW][144]
    bf16* X2 = (bf16*)S1;                 // [ref | aligned] HWC 192c
    bf16* r1 = (bf16*)S2;
    bf16* wtb = (bf16*)S2 + 4800000;      // tail at S2+9.6 MB
    bf16* wt_coff = wtb;                  // 124416
    bf16* wt_ref1 = wt_coff + 124416;     // 165888
    bf16* wt_ref2 = wt_ref1 + 165888;     // 82944
    float* dwT = (float*)(wt_ref2 + 82944);  // 864*96 fp32

    dim3 blk(256);
    auto nb = [](long n) { return dim3((unsigned)((n + 255) / 256)); };

    // ---- encoder (fp32-exact; split-K for occupancy) ----
    // t1: oc1 partials (ref half / inp half) -> S1,S2; fuse -> OUTS
    conv3x3_split<4><<<dim3(1536), blk, 0, stream>>>(ref_fea, 96, 96, 0,
                                                     inp_fea, 96, 96, 96,
                                                     oc1_w, 192, S1, S2, 96);
    fuse_add_k<<<nb(N_FEA), blk, 0, stream>>>(S1, S2, oc1_b, OUTS);
    // t2: oc3 partials (channels 0-47 / 48-95 of t1) -> S1,S2; fuse -> OUTS
    conv3x3_split<4><<<dim3(1536), blk, 0, stream>>>(OUTS, 48, 96, 0,
                                                     OUTS + 48 * 16384, 48, 96, 48,
                                                     oc3_w, 96, S1, S2, 96);
    fuse_add_k<<<nb(N_FEA), blk, 0, stream>>>(S1, S2, oc3_b, OUTS);
    // e1 = lrelu(conv_s2(t2, enc1)) -> S1
    conv3x3_v2<2, 1><<<dim3(2 * 96 * 4), blk, 0, stream>>>(OUTS, 96, OUTS, 0,
                                                           enc1_w, enc1_b, S1,
                                                           96, 128, 128, 1, nullptr, nullptr);
    wxform_all<<<nb(124416L + 165888 + 82944 + 82944), blk, 0, stream>>>(
        coff_w, ref1_w, ref2_w, dcn_w, wt_coff, wt_ref1, wt_ref2, dwT);
    // enc2 + fused quantization: out1 (en), out2 (q), F (q fp32)
    conv3x3_v2<2, 1><<<dim3(2 * 96), blk, 0, stream>>>(S1, 96, S1, 0,
                                                       enc2_w, enc2_b, out + OUT_EN,
                                                       96, 64, 64, 0, out + OUT_Q, F);
    // ---- decoder ----
    convt3x3_v2<0><<<dim3(2 * 96 * 4), blk, 0, stream>>>(F, dec1_w, dec1_b, S2, 32, 32, 1);
    convt3x3_v2<1><<<dim3(2 * 96 * 16), blk, 0, stream>>>(S2, dec2_w, dec2_b, de_hwc,
                                                          64, 64, 0);
    // ---- MFMA: offsets = conv(de) -> HWC bf16 ----
    mconv<0><<<dim3(512), blk, 0, stream>>>(de_hwc, wt_coff, coff_b, offs, nullptr,
                                            96, 144, 128, 128, 0);
    // ---- X2 = [ref | aligned] HWC ----
    pack_hwc<<<nb(N_FEA), blk, 0, stream>>>(ref_fea, X2, 16384, 192, 0);
    deform_lite_k<<<dim3(2 * 128 * 32), dim3(128), 0, stream>>>(ref_fea, offs,
                                                                dwT, dcn_b, X2);
    // ---- MFMA: r1 = lrelu(conv(X2, ref1)); out0 = aligned + lrelu(conv(r1, ref2)) ----
    mconv<0><<<dim3(512), blk, 0, stream>>>(X2, wt_ref1, ref1_b, r1, nullptr,
                                            192, 96, 128, 128, 1);
    mconv<3><<<dim3(512), blk, 0, stream>>>(r1, wt_ref2, ref2_b, out, X2,
                                            96, 96, 128, 128, 1);
}

// Round 12
// 1489.976 us; speedup vs baseline: 1.1895x; 1.0257x over previous
//
#include <hip/hip_runtime.h>
#include <hip/hip_bf16.h>

typedef __hip_bfloat16 bf16;
typedef __attribute__((ext_vector_type(8))) short s8;   // 8 x bf16 MFMA A/B frag
typedef __attribute__((ext_vector_type(4))) float f4;   // MFMA C/D frag

#define N_FEA   3145728   // 2*96*128*128
#define N_EN    196608    // 2*96*32*32
#define N_E1    786432    // 2*96*64*64
#define OUT_EN  3145728
#define OUT_Q   3342336

__device__ __forceinline__ float b2f(bf16 v) { return __bfloat162float(v); }

// ---- split-K stride-1 direct conv, 128x128, PX=4, OCB oc/block ----
template <int OCB>
__global__ __launch_bounds__(256) void conv3x3_split(
    const float* __restrict__ inA, int cA, int bstrA, int wofsA,
    const float* __restrict__ inB, int cB, int bstrB, int wofsB,
    const float* __restrict__ w, int wstride,
    float* __restrict__ P0, float* __restrict__ P1, int Cout) {
    const int H = 128, W = 128;
    const int NOC = Cout / OCB;
    int bid = blockIdx.x;
    const int ks = bid & 1;
    int r = bid >> 1;
    const int strip = r & 15; r >>= 4;
    const int ocg = r % NOC;
    const int b = r / NOC;
    const int oc0 = ocg * OCB;
    const float* in = ks ? inB : inA;
    const int cN = ks ? cB : cA;
    const int bstr = ks ? bstrB : bstrA;
    const int wofs = ks ? wofsB : wofsA;
    float* P = ks ? P1 : P0;
    __shared__ float wl[OCB * 96 * 9];
    for (int i = threadIdx.x; i < OCB * cN * 9; i += 256) {
        int o = i / (cN * 9), rem = i % (cN * 9);
        int c = rem / 9, k = rem % 9;
        wl[i] = w[((long)(oc0 + o) * wstride + wofs + c) * 9 + k];
    }
    __syncthreads();
    const int pix = strip * 1024 + threadIdx.x * 4;
    const int oy = pix >> 7, oxb = pix & 127;
    const int iy0 = oy - 1, ixb = oxb - 1;
    float acc[OCB][4];
#pragma unroll
    for (int o = 0; o < OCB; ++o)
#pragma unroll
        for (int j = 0; j < 4; ++j) acc[o][j] = 0.f;
    const bool fast = (ixb >= 0) && (ixb + 5 < W);

    const float* pl = in + (long)b * bstr * H * W;
    for (int c = 0; c < cN; ++c) {
#pragma unroll
        for (int ky = 0; ky < 3; ++ky) {
            int iy = iy0 + ky;
            if ((unsigned)iy >= (unsigned)H) continue;
            const float* row = pl + (long)iy * W + ixb;
            float rr[6];
            if (fast) {
#pragma unroll
                for (int i = 0; i < 6; ++i) rr[i] = row[i];
            } else {
#pragma unroll
                for (int i = 0; i < 6; ++i) {
                    int col = ixb + i;
                    rr[i] = ((unsigned)col < (unsigned)W) ? row[i] : 0.f;
                }
            }
#pragma unroll
            for (int o = 0; o < OCB; ++o) {
                const float* wv = &wl[(o * cN + c) * 9 + ky * 3];
#pragma unroll
                for (int j = 0; j < 4; ++j)
#pragma unroll
                    for (int kx = 0; kx < 3; ++kx)
                        acc[o][j] = fmaf(rr[j + kx], wv[kx], acc[o][j]);
            }
        }
        pl += (long)H * W;
    }
#pragma unroll
    for (int o = 0; o < OCB; ++o) {
        long idx = (((long)b * Cout + oc0 + o) * H + oy) * W + oxb;
#pragma unroll
        for (int j = 0; j < 4; ++j) P[idx + j] = acc[o][j];
    }
}

// out = lrelu(bias + p0 + p1)
__global__ void fuse_add_k(const float* __restrict__ p0, const float* __restrict__ p1,
                           const float* __restrict__ bias, float* __restrict__ out) {
    long idx = (long)blockIdx.x * 256 + threadIdx.x;
    if (idx >= (long)N_FEA) return;
    int oc = (int)((idx >> 14) % 96);
    float a = bias[oc] + p0[idx] + p1[idx];
    out[idx] = a > 0.f ? a : 0.1f * a;
}

// ---------------- generic direct conv (stride 2 users), PX=4 ----------------
template <int S, int OCB>
__global__ __launch_bounds__(256, 2) void conv3x3_v2(
    const float* __restrict__ in0, int c0,
    const float* __restrict__ in1, int c1,
    const float* __restrict__ w, const float* __restrict__ bias,
    float* __restrict__ out,
    int Cout, int Hin, int Win, int relu,
    float* __restrict__ qq, float* __restrict__ qf2) {
    const int Hout = (Hin - 1) / S + 1, Wout = (Win - 1) / S + 1;
    const int strips = (Hout * Wout) / 1024;
    int bid = blockIdx.x;
    const int strip = bid % strips; bid /= strips;
    const int oc0 = (bid % (Cout / OCB)) * OCB;
    const int b = bid / (Cout / OCB);
    const int Cin = c0 + c1;
    __shared__ float wl[OCB * 1728];
    for (int i = threadIdx.x; i < OCB * Cin * 9; i += 256) {
        int o = i / (Cin * 9), rem = i % (Cin * 9);
        wl[i] = w[(long)(oc0 + o) * Cin * 9 + rem];
    }
    __syncthreads();
    const int pix = strip * 1024 + threadIdx.x * 4;
    const int oy = pix / Wout, oxb = pix % Wout;
    const int iy0 = oy * S - 1, ixb = oxb * S - 1;
    constexpr int NX = 3 * S + 3;
    float acc[OCB][4];
#pragma unroll
    for (int o = 0; o < OCB; ++o) {
        float bz = bias[oc0 + o];
#pragma unroll
        for (int j = 0; j < 4; ++j) acc[o][j] = bz;
    }
    const bool fast = (ixb >= 0) && (ixb + NX - 1 < Win);

    auto seg = [&](const float* base, int nc, int wofs) {
        const float* pl = base + (long)b * nc * Hin * Win;
        for (int c = 0; c < nc; ++c) {
#pragma unroll
            for (int ky = 0; ky < 3; ++ky) {
                int iy = iy0 + ky;
                if ((unsigned)iy >= (unsigned)Hin) continue;
                const float* row = pl + (long)iy * Win + ixb;
                float rr[NX];
                if (fast) {
#pragma unroll
                    for (int i = 0; i < NX; ++i) rr[i] = row[i];
                } else {
#pragma unroll
                    for (int i = 0; i < NX; ++i) {
                        int col = ixb + i;
                        rr[i] = ((unsigned)col < (unsigned)Win) ? row[i] : 0.f;
                    }
                }
#pragma unroll
                for (int o = 0; o < OCB; ++o) {
                    const float* wv = &wl[(o * Cin + wofs + c) * 9 + ky * 3];
#pragma unroll
                    for (int j = 0; j < 4; ++j)
#pragma unroll
                        for (int kx = 0; kx < 3; ++kx)
                            acc[o][j] = fmaf(rr[j * S + kx], wv[kx], acc[o][j]);
                }
            }
            pl += (long)Hin * Win;
        }
    };
    seg(in0, c0, 0);
    seg(in1, c1, c0);

#pragma unroll
    for (int o = 0; o < OCB; ++o) {
        long idx = (((long)b * Cout + oc0 + o) * Hout + oy) * Wout + oxb;
#pragma unroll
        for (int j = 0; j < 4; ++j) {
            float a = acc[o][j];
            if (relu) a = a > 0.f ? a : 0.1f * a;
            out[idx + j] = a;
            if (qq) {
                float q = rintf(a);
                qq[idx + j] = q;
                qf2[idx + j] = q;
            }
        }
    }
}

// ------------- ConvTranspose2d(96->96,k3,s2,p1,op1), gather, 4 ox/thread --------------
template <int HWC>
__global__ __launch_bounds__(256) void convt3x3_v2(
    const float* __restrict__ in, const float* __restrict__ w,
    const float* __restrict__ bias, void* __restrict__ out,
    int Hin, int Win, int relu) {
    const int C = 96;
    const int Hout = 2 * Hin, Wout = 2 * Win;
    const int strips = (Hout * Wout) / 1024;
    int bid = blockIdx.x;
    const int strip = bid % strips; bid /= strips;
    const int oc = bid % C;
    const int b = bid / C;
    __shared__ float wl[864];
    for (int i = threadIdx.x; i < C * 9; i += 256) {
        int c = i / 9, k = i % 9;
        wl[i] = w[((long)c * C + oc) * 9 + k];
    }
    __syncthreads();
    const int pix = strip * 1024 + threadIdx.x * 4;
    const int oy = pix / Wout, oxb = pix % Wout;
    const int c0x = oxb >> 1;
    const int oyE = oy + 1;
    float acc[4];
    const float bz = bias[oc];
#pragma unroll
    for (int j = 0; j < 4; ++j) acc[j] = bz;
    const bool r2ok = (c0x + 2) < Win;

    const float* pl = in + (long)b * C * Hin * Win;
    for (int c = 0; c < C; ++c) {
        float wv[9];
#pragma unroll
        for (int k = 0; k < 9; ++k) wv[k] = wl[c * 9 + k];
#pragma unroll
        for (int ky = 0; ky < 3; ++ky) {
            int ty = oyE - ky;
            if (ty & 1) continue;
            int iy = ty >> 1;
            if ((unsigned)iy >= (unsigned)Hin) continue;
            const float* row = pl + (long)iy * Win + c0x;
            float r0 = row[0];
            float r1 = row[1];
            float r2 = r2ok ? row[2] : 0.f;
            acc[0] = fmaf(r0, wv[ky * 3 + 1], acc[0]);
            acc[1] = fmaf(r1, wv[ky * 3 + 0], acc[1]);
            acc[1] = fmaf(r0, wv[ky * 3 + 2], acc[1]);
            acc[2] = fmaf(r1, wv[ky * 3 + 1], acc[2]);
            acc[3] = fmaf(r2, wv[ky * 3 + 0], acc[3]);
            acc[3] = fmaf(r1, wv[ky * 3 + 2], acc[3]);
        }
        pl += (long)Hin * Win;
    }
#pragma unroll
    for (int j = 0; j < 4; ++j) {
        float a = acc[j];
        if (relu) a = a > 0.f ? a : 0.1f * a;
        if (HWC)
            ((bf16*)out)[((long)b * Hout * Wout + oy * Wout + oxb + j) * 96 + oc] =
                __float2bfloat16(a);
        else
            ((float*)out)[(((long)b * C + oc) * Hout + oy) * Wout + oxb + j] = a;
    }
}

// -------- combined weight transforms: 3x MFMA-B pack + dcn MFMA-B pack ------
__device__ __forceinline__ void packw(const float* __restrict__ w, bf16* __restrict__ wP,
                                      int Cin, int swap, long i) {
    const int cpt = Cin >> 5;
    int e = (int)(i & 7);
    int n16 = (int)((i >> 3) & 15);
    int q = (int)((i >> 7) & 3);
    long t = i >> 9;
    int ci = (int)(t % cpt); t /= cpt;
    int tap = (int)(t % 9);
    int g = (int)(t / 9);
    int oc = g * 16 + n16;
    int c = ci * 32 + q * 8 + e;
    int cs = swap ? (c + Cin / 2) % Cin : c;
    wP[i] = __float2bfloat16(w[((long)oc * Cin + cs) * 9 + tap]);
}
__global__ void wxform_all(const float* __restrict__ coffw, const float* __restrict__ ref1w,
                           const float* __restrict__ ref2w, const float* __restrict__ dcnw,
                           bf16* __restrict__ p_coff, bf16* __restrict__ p_ref1,
                           bf16* __restrict__ p_ref2, bf16* __restrict__ p_dcn) {
    const long n1 = 124416, n2 = 165888, n3 = 82944, n4 = 82944;
    long i = (long)blockIdx.x * 256 + threadIdx.x;
    if (i < n1) { packw(coffw, p_coff, 96, 0, i); return; }
    i -= n1;
    if (i < n2) { packw(ref1w, p_ref1, 192, 1, i); return; }
    i -= n2;
    if (i < n3) { packw(ref2w, p_ref2, 96, 0, i); return; }
    i -= n3;
    if (i < n4) {
        // dcn: K=864 GEMM-B pack [g][ci][lane][8]; k = ci*32 + q*8 + e, oc = g*16+n16
        int e = (int)(i & 7);
        int n16 = (int)((i >> 3) & 15);
        int q = (int)((i >> 7) & 3);
        long t = i >> 9;
        int ci = (int)(t % 27);
        int g = (int)(t / 27);
        p_dcn[i] = __float2bfloat16(dcnw[(long)(g * 16 + n16) * 864 + ci * 32 + q * 8 + e]);
    }
}

// -------- pack fp32 NCHW (96 ch) -> bf16 HWC [b][y][x][Cs] at channel offset --------
__global__ void pack_hwc(const float* __restrict__ src, bf16* __restrict__ dst,
                         int HW, int Cs, int coff) {
    long i = (long)blockIdx.x * 256 + threadIdx.x;
    if (i >= 2L * 96 * HW) return;
    int px = (int)(i % HW);
    long t = i / HW;
    int c = (int)(t % 96);
    int b = (int)(t / 96);
    dst[((long)b * HW + px) * Cs + coff + c] = __float2bfloat16(src[i]);
}

// ----------------- MFMA implicit-GEMM 3x3 conv (stride 1, 128x128) -----------------
template <int EPI>
__global__ __launch_bounds__(256) void mconv(
    const bf16* __restrict__ X, const bf16* __restrict__ wP,
    const float* __restrict__ bias, void* __restrict__ out,
    const bf16* __restrict__ res,
    int Cin, int Cout, int H, int W, int relu) {
    const int HW = H * W;
    const int NG = Cout >> 4, split = (NG + 1) >> 1;
    int bid = blockIdx.x;
    const int nb = HW >> 6;
    const int pxb = (bid % nb) << 6;
    const int b = bid / nb;
    const int wave = threadIdx.x >> 6, lane = threadIdx.x & 63;
    const int mt = (wave >> 1) << 5;
    const int og0 = (wave & 1) ? split : 0;
    const int og1 = (wave & 1) ? NG : split;
    const int q = lane >> 4, n16 = lane & 15;
    const int pA0 = pxb + mt + n16, pA1 = pA0 + 16;
    const int oy0 = pA0 / W, ox0 = pA0 % W;
    const int oy1 = pA1 / W, ox1 = pA1 % W;
    const long ib = (long)b * HW * Cin;
    f4 acc0[5], acc1[5];
    const f4 z4 = {0.f, 0.f, 0.f, 0.f};
#pragma unroll
    for (int g = 0; g < 5; ++g) { acc0[g] = z4; acc1[g] = z4; }
    const s8 z8 = {0, 0, 0, 0, 0, 0, 0, 0};
    const int cpt = Cin >> 5;
    const int lofs = lane << 3;
    for (int tap = 0; tap < 9; ++tap) {
        const int ky = tap / 3 - 1, kx = tap % 3 - 1;
        const int iy0 = oy0 + ky, ix0 = ox0 + kx;
        const int iy1 = oy1 + ky, ix1 = ox1 + kx;
        const bool v0 = (unsigned)iy0 < (unsigned)H && (unsigned)ix0 < (unsigned)W;
        const bool v1 = (unsigned)iy1 < (unsigned)H && (unsigned)ix1 < (unsigned)W;
        const bf16* pa0 = X + ib + ((long)iy0 * W + ix0) * Cin + q * 8;
        const bf16* pa1 = X + ib + ((long)iy1 * W + ix1) * Cin + q * 8;
        for (int ci = 0; ci < cpt; ++ci) {
            const int c0 = ci << 5;
            s8 a0 = v0 ? *(const s8*)(pa0 + c0) : z8;
            s8 a1 = v1 ? *(const s8*)(pa1 + c0) : z8;
#pragma unroll
            for (int gi = 0; gi < 5; ++gi) {
                int g = og0 + gi;
                if (g >= og1) break;
                s8 bb = *(const s8*)(wP + ((long)(g * 9 + tap) * cpt + ci) * 512 + lofs);
                acc0[gi] = __builtin_amdgcn_mfma_f32_16x16x32_bf16(a0, bb, acc0[gi], 0, 0, 0);
                acc1[gi] = __builtin_amdgcn_mfma_f32_16x16x32_bf16(a1, bb, acc1[gi], 0, 0, 0);
            }
        }
    }
#pragma unroll
    for (int gi = 0; gi < 5; ++gi) {
        int g = og0 + gi;
        if (g >= og1) break;
        int oc = g * 16 + n16;
        float bz = bias[oc];
#pragma unroll
        for (int t = 0; t < 2; ++t) {
            f4 a = t ? acc1[gi] : acc0[gi];
            int pxl = pxb + mt + t * 16 + q * 4;
#pragma unroll
            for (int r = 0; r < 4; ++r) {
                float v = a[r] + bz;
                if (relu) v = v > 0.f ? v : 0.1f * v;
                int px = pxl + r;
                if (EPI == 0)
                    ((bf16*)out)[((long)b * HW + px) * Cout + oc] = __float2bfloat16(v);
                else {
                    v += b2f(res[((long)b * HW + px) * 192 + 96 + oc]);
                    ((float*)out)[((long)b * Cout + oc) * HW + px] = v;
                }
            }
        }
    }
}

// -------- DCNv1: bilinear sample (VALU) + MFMA contraction.
// Block = 32 px of one row (2 m-tiles), 256 thr. offs bf16 HWC; wD packed
// [g][ci][lane][8]; writes aligned into X2 HWC channels 96..191. --------
__global__ __launch_bounds__(256) void deform_m_k(
    const float* __restrict__ x, const bf16* __restrict__ offs,
    const bf16* __restrict__ wD, const float* __restrict__ db,
    bf16* __restrict__ X2) {
    const int H = 128, W = 128, C = 96;
    __shared__ bf16 offL[32 * 144];
    __shared__ bf16 s[32][872];          // 864 + 8 pad (16B) -> ~2-way LDS reads
    int bid = blockIdx.x;
    const int band = bid & 7;            // XCD residue -> 16-row band
    int r = bid >> 3;
    const int b = r >> 6; r &= 63;
    const int rowin = r >> 2, xb = r & 3;
    const int oy = band * 16 + rowin;
    const int ox0 = xb * 32;
    const int tid = threadIdx.x;
    const long pxbase = (long)b * (H * W) + oy * W + ox0;
    // stage offsets (coalesced: lanes -> consecutive cc)
    for (int e = tid; e < 32 * 144; e += 256)
        offL[e] = offs[(pxbase + (e / 144)) * 144 + (e % 144)];
    __syncthreads();
    // phase 2: bilinear sampling -> s[px][k], k = c*9+kk (lanes -> consecutive k)
    for (int e = tid; e < 32 * 864; e += 256) {
        int k = e % 864, p = e / 864;
        int c = k / 9, kk = k % 9, g8 = c / 12;
        int ox = ox0 + p;
        float offy = b2f(offL[p * 144 + g8 * 18 + kk * 2]);
        float offx = b2f(offL[p * 144 + g8 * 18 + kk * 2 + 1]);
        float py = (float)(oy + kk / 3 - 1) + offy;
        float px = (float)(ox + kk % 3 - 1) + offx;
        float y0f = floorf(py), x0f = floorf(px);
        float ly = py - y0f, lx = px - x0f;
        int y0 = (int)y0f, x0 = (int)x0f;
        const float* pl = x + ((long)b * C + c) * (long)H * W;
        float w00 = (1.f - ly) * (1.f - lx), w01 = (1.f - ly) * lx;
        float w10 = ly * (1.f - lx), w11 = ly * lx;
        float v = 0.f;
        if ((unsigned)y0 < (unsigned)H && (unsigned)x0 < (unsigned)W)
            v = fmaf(pl[y0 * W + x0], w00, v);
        if ((unsigned)y0 < (unsigned)H && (unsigned)(x0 + 1) < (unsigned)W)
            v = fmaf(pl[y0 * W + x0 + 1], w01, v);
        if ((unsigned)(y0 + 1) < (unsigned)H && (unsigned)x0 < (unsigned)W)
            v = fmaf(pl[(y0 + 1) * W + x0], w10, v);
        if ((unsigned)(y0 + 1) < (unsigned)H && (unsigned)(x0 + 1) < (unsigned)W)
            v = fmaf(pl[(y0 + 1) * W + x0 + 1], w11, v);
        s[p][k] = __float2bfloat16(v);
    }
    __syncthreads();
    // phase 3: MFMA [16px x 864] x [864 x 96oc]; 12 tasks over 4 waves
    const int wave = tid >> 6, lane = tid & 63;
    const int q = lane >> 4, n16 = lane & 15;
    const f4 z4 = {0.f, 0.f, 0.f, 0.f};
#pragma unroll
    for (int i = 0; i < 3; ++i) {
        int task = wave * 3 + i;
        int g = task % 6, mt = (task / 6) << 4;
        f4 acc = z4;
        const bf16* wg = wD + (long)g * 27 * 512 + (lane << 3);
#pragma unroll 3
        for (int ci = 0; ci < 27; ++ci) {
            s8 a = *(const s8*)&s[mt + n16][ci * 32 + q * 8];
            s8 bb = *(const s8*)(wg + ci * 512);
            acc = __builtin_amdgcn_mfma_f32_16x16x32_bf16(a, bb, acc, 0, 0, 0);
        }
        int oc = g * 16 + n16;
        float bz = db[oc];
#pragma unroll
        for (int rr = 0; rr < 4; ++rr) {
            int p = mt + q * 4 + rr;       // D row = q*4 + reg
            X2[(pxbase + p) * 192 + 96 + oc] = __float2bfloat16(acc[rr] + bz);
        }
    }
}

extern "C" void kernel_launch(void* const* d_in, const int* in_sizes, int n_in,
                              void* d_out, int out_size, void* d_ws, size_t ws_size,
                              hipStream_t stream) {
    const float* ref_fea = (const float*)d_in[0];
    const float* inp_fea = (const float*)d_in[1];
    const float* oc1_w = (const float*)d_in[2];  const float* oc1_b = (const float*)d_in[3];
    const float* oc3_w = (const float*)d_in[4];  const float* oc3_b = (const float*)d_in[5];
    const float* enc1_w = (const float*)d_in[6]; const float* enc1_b = (const float*)d_in[7];
    const float* enc2_w = (const float*)d_in[8]; const float* enc2_b = (const float*)d_in[9];
    const float* dec1_w = (const float*)d_in[10]; const float* dec1_b = (const float*)d_in[11];
    const float* dec2_w = (const float*)d_in[12]; const float* dec2_b = (const float*)d_in[13];
    const float* coff_w = (const float*)d_in[14]; const float* coff_b = (const float*)d_in[15];
    const float* dcn_w = (const float*)d_in[16];  const float* dcn_b = (const float*)d_in[17];
    const float* ref1_w = (const float*)d_in[18]; const float* ref1_b = (const float*)d_in[19];
    const float* ref2_w = (const float*)d_in[20]; const float* ref2_b = (const float*)d_in[21];

    float* out = (float*)d_out;
    float* OUTS = out;                    // out0 region as fp32 scratch (t1/t2)
    float* S1 = (float*)d_ws;             // 12.58 MB slot
    float* S2 = S1 + N_FEA;               // 12.58 MB slot
    float* F = S1 + N_E1;                 // q fp32 (after e1 region)
    bf16* de_hwc = (bf16*)S1;
    bf16* offs = (bf16*)S2;               // HWC [b][HW][144]
    bf16* X2 = (bf16*)S1;                 // [ref | aligned] HWC 192c
    bf16* r1 = (bf16*)S2;
    bf16* wtb = (bf16*)S2 + 4800000;      // tail at S2+9.6 MB
    bf16* wt_coff = wtb;                  // 124416
    bf16* wt_ref1 = wt_coff + 124416;     // 165888
    bf16* wt_ref2 = wt_ref1 + 165888;     // 82944
    bf16* wt_dcn = wt_ref2 + 82944;       // 82944 (MFMA-B pack)

    dim3 blk(256);
    auto nb = [](long n) { return dim3((unsigned)((n + 255) / 256)); };

    // ---- encoder (fp32-exact; split-K for occupancy) ----
    conv3x3_split<4><<<dim3(1536), blk, 0, stream>>>(ref_fea, 96, 96, 0,
                                                     inp_fea, 96, 96, 96,
                                                     oc1_w, 192, S1, S2, 96);
    fuse_add_k<<<nb(N_FEA), blk, 0, stream>>>(S1, S2, oc1_b, OUTS);
    conv3x3_split<4><<<dim3(1536), blk, 0, stream>>>(OUTS, 48, 96, 0,
                                                     OUTS + 48 * 16384, 48, 96, 48,
                                                     oc3_w, 96, S1, S2, 96);
    fuse_add_k<<<nb(N_FEA), blk, 0, stream>>>(S1, S2, oc3_b, OUTS);
    conv3x3_v2<2, 1><<<dim3(2 * 96 * 4), blk, 0, stream>>>(OUTS, 96, OUTS, 0,
                                                           enc1_w, enc1_b, S1,
                                                           96, 128, 128, 1, nullptr, nullptr);
    wxform_all<<<nb(124416L + 165888 + 82944 + 82944), blk, 0, stream>>>(
        coff_w, ref1_w, ref2_w, dcn_w, wt_coff, wt_ref1, wt_ref2, wt_dcn);
    conv3x3_v2<2, 1><<<dim3(2 * 96), blk, 0, stream>>>(S1, 96, S1, 0,
                                                       enc2_w, enc2_b, out + OUT_EN,
                                                       96, 64, 64, 0, out + OUT_Q, F);
    // ---- decoder ----
    convt3x3_v2<0><<<dim3(2 * 96 * 4), blk, 0, stream>>>(F, dec1_w, dec1_b, S2, 32, 32, 1);
    convt3x3_v2<1><<<dim3(2 * 96 * 16), blk, 0, stream>>>(S2, dec2_w, dec2_b, de_hwc,
                                                          64, 64, 0);
    // ---- MFMA: offsets = conv(de) -> HWC bf16 ----
    mconv<0><<<dim3(512), blk, 0, stream>>>(de_hwc, wt_coff, coff_b, offs, nullptr,
                                            96, 144, 128, 128, 0);
    // ---- X2 = [ref | aligned] HWC ----
    pack_hwc<<<nb(N_FEA), blk, 0, stream>>>(ref_fea, X2, 16384, 192, 0);
    deform_m_k<<<dim3(1024), blk, 0, stream>>>(ref_fea, offs, wt_dcn, dcn_b, X2);
    // ---- MFMA: r1 = lrelu(conv(X2, ref1)); out0 = aligned + lrelu(conv(r1, ref2)) ----
    mconv<0><<<dim3(512), blk, 0, stream>>>(X2, wt_ref1, ref1_b, r1, nullptr,
                                            192, 96, 128, 128, 1);
    mconv<3><<<dim3(512), blk, 0, stream>>>(r1, wt_ref2, ref2_b, out, X2,
                                            96, 96, 128, 128, 1);
}